// Round 6
// baseline (163.018 us; speedup 1.0000x reference)
//
#include <hip/hip_runtime.h>
#include <hip/hip_bf16.h>

// Chamfer distance: B=8, N=M=4096, D=128, fp32 inputs, scalar fp32 out.
// dist[b,n,m] = ||p1||^2 + ||p2||^2 - 2*p1.p2
// bf1 holds (-2*p1) in bf16, so MFMA acc = -2*cross directly.
// Directional mins kept as biased-float-as-uint atomicMin (bias 16384 makes
// all keys positive; uint order == float order for positive floats).

#define BATCH 8
#define NPTS 4096
#define DIM 128
#define FBIAS 16384.0f

using bf16x8 = __attribute__((ext_vector_type(8))) short;
using f32x4  = __attribute__((ext_vector_type(4))) float;

// ------------- K1: fp32 -> bf16 (p1 scaled by -2) + exact fp32 norms --------
__global__ void prep_kernel(const float* __restrict__ p1,
                            const float* __restrict__ p2,
                            __hip_bfloat16* __restrict__ b1,
                            __hip_bfloat16* __restrict__ b2,
                            float* __restrict__ s1,
                            float* __restrict__ s2) {
    const int arr = blockIdx.y;
    const float* src = arr ? p2 : p1;
    __hip_bfloat16* dst = arr ? b2 : b1;
    float* sq = arr ? s2 : s1;
    const float scale = arr ? 1.0f : -2.0f;

    const int wid = threadIdx.x >> 6;
    const int l   = threadIdx.x & 63;
    const int p   = blockIdx.x * 4 + wid;   // one wave per point
    const float2 v = *reinterpret_cast<const float2*>(src + (size_t)p * DIM + l * 2);
    float s = v.x * v.x + v.y * v.y;        // norm from ORIGINAL values
    __hip_bfloat162 h = __float22bfloat162_rn(make_float2(v.x * scale, v.y * scale));
    *reinterpret_cast<__hip_bfloat162*>(dst + (size_t)p * DIM + l * 2) = h;
    #pragma unroll
    for (int off = 1; off < 64; off <<= 1) s += __shfl_xor(s, off);
    if (l == 0) sq[p] = s;
}

// async global->LDS, 16B per lane; lds base must be wave-uniform.
__device__ __forceinline__ void stage16(const __hip_bfloat16* g, void* lds) {
    __builtin_amdgcn_global_load_lds(
        (const __attribute__((address_space(1))) void*)g,
        (__attribute__((address_space(3))) void*)lds, 16, 0, 0);
}

// ------------- K2: tiled GEMM + fused directional mins ----------------------
// 1-D grid of 1024 blocks; b = id&7 so XCD k (round-robin dispatch) only
// touches batch k -> per-XCD L2 working set = 2MB bf16 data.
// Block: 128 rows x 1024 cols as 16 m-tiles of 64 cols. Wave: 32 rows.
// B-tile (64 rows x 256B = 16KB) double-buffered -> LDS 32KB -> 4-5 blocks/CU;
// regs ~112 (80 VGPR + 32 AGPR acc) -> 4 waves/SIMD. This is the occupancy
// round: R1-R5 were stuck at ~19% (2 blocks/CU) and every pipe sat idle.
// launch_bounds (256,2): forcing (256,4) made the allocator cut to 64 VGPR
// -> scratch spills (R2: FETCH 37->239MB, K2 63->128us). Do NOT force.
__global__ void __launch_bounds__(256, 2)
chamfer_tile_kernel(const __hip_bfloat16* __restrict__ bf1,
                    const __hip_bfloat16* __restrict__ bf2,
                    const float* __restrict__ sq1,
                    const float* __restrict__ sq2,
                    unsigned int* __restrict__ min1u,   // [B][NPTS] biased keys
                    unsigned int* __restrict__ min2u) { // [B][NPTS] biased keys
    const int lin = blockIdx.x;
    const int b   = lin & 7;          // XCD-aligned batch
    const int rest = lin >> 3;
    const int nt  = rest & 31;        // n-tile (128 rows)
    const int mh  = rest >> 5;        // m quarter (1024 cols)
    const int tid = threadIdx.x;
    const int wid = tid >> 6;
    const int l   = tid & 63;
    const int l15 = l & 15;
    const int lhi = l >> 4;

    __shared__ __align__(16) unsigned char btile[2][64 * 256]; // 2 x 16KB

    const __hip_bfloat16* bf1b = bf1 + (size_t)b * NPTS * DIM;
    const __hip_bfloat16* bf2b = bf2 + (size_t)b * NPTS * DIM;
    const float* sq2b = sq2 + b * NPTS;

    const int n0 = nt * 128 + wid * 32;  // wave's first row

    // A fragments: rows n0 + rt*16 + l15, k = ks*32 + lhi*8
    bf16x8 afrag[2][4];
    #pragma unroll
    for (int rt = 0; rt < 2; ++rt)
        #pragma unroll
        for (int ks = 0; ks < 4; ++ks)
            afrag[rt][ks] = *reinterpret_cast<const bf16x8*>(
                bf1b + (n0 + rt * 16 + l15) * DIM + ks * 32 + lhi * 8);

    // sq1 for accumulator rows: n0 + rt*16 + lhi*4 + j
    float sq1v[2][4];
    #pragma unroll
    for (int rt = 0; rt < 2; ++rt)
        #pragma unroll
        for (int j = 0; j < 4; ++j)
            sq1v[rt][j] = sq1[b * NPTS + n0 + rt * 16 + lhi * 4 + j];

    float rmin[2][4];
    #pragma unroll
    for (int rt = 0; rt < 2; ++rt)
        #pragma unroll
        for (int j = 0; j < 4; ++j) rmin[rt][j] = 3.4e38f;

    // wave-level stage of 64-row B tile at column m0 into buffer `buf`.
    // linear LDS slot (row,q) <- global column-block (q ^ (row&7)), so the
    // swizzled read  btile[row*256 + (kbyte ^ ((row&7)<<4))]  sees k=kbyte/2.
    auto STAGE = [&](int buf, int m0) {
        #pragma unroll
        for (int j = 0; j < 4; ++j) {
            const int c   = j * 256 + wid * 64 + l;   // [0, 1024)
            const int row = c >> 4;
            const int q   = c & 15;
            const __hip_bfloat16* src =
                bf2b + (size_t)(m0 + row) * DIM + (q ^ (row & 7)) * 8;
            stage16(src, &btile[buf][(j * 256 + wid * 64) * 16]);
        }
    };

    int cur = 0;
    STAGE(0, mh * 1024);
    __syncthreads();   // compiler drains vmcnt before the barrier

    for (int mt = 0; mt < 16; ++mt) {
        const int m0 = mh * 1024 + mt * 64;
        if (mt < 15) STAGE(cur ^ 1, m0 + 64);  // prefetch next tile

        // MFMA: acc = (-2*P1rows) x P2rows^T, K=128, 64 cols
        f32x4 acc[2][4];
        #pragma unroll
        for (int rt = 0; rt < 2; ++rt)
            #pragma unroll
            for (int ct = 0; ct < 4; ++ct) acc[rt][ct] = f32x4{0.f, 0.f, 0.f, 0.f};

        #pragma unroll
        for (int ks = 0; ks < 4; ++ks) {
            #pragma unroll
            for (int ct = 0; ct < 4; ++ct) {
                const int brow = ct * 16 + l15;
                const int kbyte = ks * 64 + lhi * 16;
                bf16x8 bfrag = *reinterpret_cast<const bf16x8*>(
                    &btile[cur][brow * 256 + (kbyte ^ ((brow & 7) << 4))]);
                #pragma unroll
                for (int rt = 0; rt < 2; ++rt)
                    acc[rt][ct] = __builtin_amdgcn_mfma_f32_16x16x32_bf16(
                        afrag[rt][ks], bfrag, acc[rt][ct], 0, 0, 0);
            }
        }

        // per-lane sq2 values for each col group (L1-resident)
        float s2v[4];
        #pragma unroll
        for (int ct = 0; ct < 4; ++ct) s2v[ct] = sq2b[m0 + ct * 16 + l15];

        // dir1: row-mins (min over cols), min3-friendly pairs over ct
        #pragma unroll
        for (int rt = 0; rt < 2; ++rt)
            #pragma unroll
            for (int j = 0; j < 4; ++j) {
                float r = rmin[rt][j];
                #pragma unroll
                for (int cp = 0; cp < 2; ++cp) {
                    const float t0 = acc[rt][2 * cp][j]     + s2v[2 * cp];
                    const float t1 = acc[rt][2 * cp + 1][j] + s2v[2 * cp + 1];
                    r = fminf(r, fminf(t0, t1));   // v_min3
                }
                rmin[rt][j] = r;
            }

        // dir2: col-mins (min over this wave's 32 rows), pairs over j
        float cmin[4];
        #pragma unroll
        for (int ct = 0; ct < 4; ++ct) {
            float c = 3.4e38f;
            #pragma unroll
            for (int rt = 0; rt < 2; ++rt)
                #pragma unroll
                for (int jp = 0; jp < 2; ++jp) {
                    const float u0 = sq1v[rt][2 * jp]     + acc[rt][ct][2 * jp];
                    const float u1 = sq1v[rt][2 * jp + 1] + acc[rt][ct][2 * jp + 1];
                    c = fminf(c, fminf(u0, u1));   // v_min3
                }
            cmin[ct] = c;
        }

        // fold the 4 lhi row-groups; all lanes end with the full col-min
        #pragma unroll
        for (int ct = 0; ct < 4; ++ct) {
            cmin[ct] = fminf(cmin[ct], __shfl_xor(cmin[ct], 16));
            cmin[ct] = fminf(cmin[ct], __shfl_xor(cmin[ct], 32));
        }
        // lane l owns col l of this tile: select its ct via cndmask chain
        // (compile-time-indexed reads only; runtime cmin[lhi] would spill)
        {
            float v = cmin[0];
            v = (lhi == 1) ? cmin[1] : v;
            v = (lhi == 2) ? cmin[2] : v;
            v = (lhi == 3) ? cmin[3] : v;
            atomicMin(&min2u[(size_t)b * NPTS + m0 + l],
                      __float_as_uint(v + FBIAS));
        }

        __syncthreads();   // next-tile loads landed AND everyone done reading cur
        cur ^= 1;
    }

    // dir1 finalize: reduce across lane bits 0..3 (cols), one atomic per row
    #pragma unroll
    for (int rt = 0; rt < 2; ++rt)
        #pragma unroll
        for (int j = 0; j < 4; ++j) {
            float v = rmin[rt][j];
            v = fminf(v, __shfl_xor(v, 1));
            v = fminf(v, __shfl_xor(v, 2));
            v = fminf(v, __shfl_xor(v, 4));
            v = fminf(v, __shfl_xor(v, 8));
            rmin[rt][j] = v;
        }
    if (l15 == 0) {
        #pragma unroll
        for (int rt = 0; rt < 2; ++rt)
            #pragma unroll
            for (int j = 0; j < 4; ++j)
                atomicMin(&min1u[(size_t)b * NPTS + n0 + rt * 16 + lhi * 4 + j],
                          __float_as_uint(rmin[rt][j] + FBIAS));
    }
}

// ------------- K3: combine, means, scalar out -------------------------------
// 256 blocks x 256 threads = 65536 = 2 * B * NPTS (exact, no guards)
__global__ void finalize_kernel(const unsigned int* __restrict__ min1u,
                                const unsigned int* __restrict__ min2u,
                                const float* __restrict__ sq1,
                                const float* __restrict__ sq2,
                                float* __restrict__ out) {
    const int tid = threadIdx.x;
    const int gid = blockIdx.x * 256 + tid;
    float sum;

    if (gid < BATCH * NPTS) {
        sum = (__uint_as_float(min1u[gid]) - FBIAS + sq1[gid])
              * (1.0f / (BATCH * NPTS));
    } else {
        const int idx = gid - BATCH * NPTS;
        sum = (__uint_as_float(min2u[idx]) - FBIAS + sq2[idx])
              * (1.0f / (BATCH * NPTS));
    }

    #pragma unroll
    for (int off = 1; off < 64; off <<= 1) sum += __shfl_xor(sum, off);
    __shared__ float wsum[4];
    if ((tid & 63) == 0) wsum[tid >> 6] = sum;
    __syncthreads();
    if (tid == 0) atomicAdd(out, wsum[0] + wsum[1] + wsum[2] + wsum[3]);
}

extern "C" void kernel_launch(void* const* d_in, const int* in_sizes, int n_in,
                              void* d_out, int out_size, void* d_ws, size_t ws_size,
                              hipStream_t stream) {
    const float* p1 = (const float*)d_in[0];
    const float* p2 = (const float*)d_in[1];
    float* out = (float*)d_out;

    const size_t npts_tot = (size_t)BATCH * NPTS;
    __hip_bfloat16* bf1 = (__hip_bfloat16*)d_ws;
    __hip_bfloat16* bf2 = bf1 + npts_tot * DIM;
    float* sq1 = (float*)(bf2 + npts_tot * DIM);
    float* sq2 = sq1 + npts_tot;
    unsigned int* min1u = (unsigned int*)(sq2 + npts_tot);  // [B][NPTS]
    unsigned int* min2u = min1u + npts_tot;                 // [B][NPTS]

    hipMemsetAsync(d_out, 0, sizeof(float), stream);
    hipMemsetAsync(min1u, 0xFF, npts_tot * 2 * sizeof(unsigned int), stream);

    prep_kernel<<<dim3(npts_tot / 4, 2), 256, 0, stream>>>(p1, p2, bf1, bf2, sq1, sq2);

    chamfer_tile_kernel<<<1024, 256, 0, stream>>>(bf1, bf2, sq1, sq2, min1u, min2u);

    finalize_kernel<<<256, 256, 0, stream>>>(min1u, min2u, sq1, sq2, out);
}

// Round 7
// 139.723 us; speedup vs baseline: 1.1667x; 1.1667x over previous
//
#include <hip/hip_runtime.h>
#include <hip/hip_bf16.h>

// Chamfer distance: B=8, N=M=4096, D=128, fp32 inputs, scalar fp32 out.
// dist[b,n,m] = ||p1||^2 + ||p2||^2 - 2*p1.p2
// bf1 holds (-2*p1) in bf16, so MFMA acc = -2*cross directly.
// Directional mins kept as biased-float-as-uint atomicMin (bias 16384 makes
// all keys positive; uint order == float order for positive floats).

#define BATCH 8
#define NPTS 4096
#define DIM 128
#define FBIAS 16384.0f

using bf16x8 = __attribute__((ext_vector_type(8))) short;
using f32x4  = __attribute__((ext_vector_type(4))) float;

// ------------- K1: fp32 -> bf16 (p1 scaled by -2) + exact fp32 norms --------
__global__ void prep_kernel(const float* __restrict__ p1,
                            const float* __restrict__ p2,
                            __hip_bfloat16* __restrict__ b1,
                            __hip_bfloat16* __restrict__ b2,
                            float* __restrict__ s1,
                            float* __restrict__ s2) {
    const int arr = blockIdx.y;
    const float* src = arr ? p2 : p1;
    __hip_bfloat16* dst = arr ? b2 : b1;
    float* sq = arr ? s2 : s1;
    const float scale = arr ? 1.0f : -2.0f;

    const int wid = threadIdx.x >> 6;
    const int l   = threadIdx.x & 63;
    const int p   = blockIdx.x * 4 + wid;   // one wave per point
    const float2 v = *reinterpret_cast<const float2*>(src + (size_t)p * DIM + l * 2);
    float s = v.x * v.x + v.y * v.y;        // norm from ORIGINAL values
    __hip_bfloat162 h = __float22bfloat162_rn(make_float2(v.x * scale, v.y * scale));
    *reinterpret_cast<__hip_bfloat162*>(dst + (size_t)p * DIM + l * 2) = h;
    #pragma unroll
    for (int off = 1; off < 64; off <<= 1) s += __shfl_xor(s, off);
    if (l == 0) sq[p] = s;
}

// async global->LDS, 16B per lane; lds base must be wave-uniform.
__device__ __forceinline__ void stage16(const __hip_bfloat16* g, void* lds) {
    __builtin_amdgcn_global_load_lds(
        (const __attribute__((address_space(1))) void*)g,
        (__attribute__((address_space(3))) void*)lds, 16, 0, 0);
}

// ------------- K2: tiled GEMM + fused directional mins ----------------------
// 1-D grid of 1024 blocks; b = id&7 so XCD k (round-robin dispatch) only
// touches batch k -> per-XCD L2 working set = 2MB bf16 data (R6: FETCH 8.4MB).
// Block: 128 rows x 1024 cols as 16 m-tiles of 64 cols. Wave: 32 rows.
// B-tile (64 rows x 256B = 16KB) double-buffered, staged via global_load_lds
// with the XOR swizzle applied on the SOURCE address (gload_lds writes
// linearly); next tile prefetched before computing the current one.
//
// OCCUPANCY (R1-R6 evidence): the 2nd __launch_bounds__ arg PINS waves/EU on
// this toolchain: every (256,2) round measured ~19-21% occupancy regardless
// of LDS/VGPR headroom; the one (256,4) round measured 43%. Unified reg
// budget per wave at 4 waves/EU = 128; this body needs ~68 arch + 32 acc
// = ~100, so (256,4) fits WITHOUT the R3 spill (R3's acc[2][8]=64 AGPR left
// only 64 arch regs -> spilled). FETCH_SIZE is the spill canary.
__global__ void __launch_bounds__(256, 4)
chamfer_tile_kernel(const __hip_bfloat16* __restrict__ bf1,
                    const __hip_bfloat16* __restrict__ bf2,
                    const float* __restrict__ sq1,
                    const float* __restrict__ sq2,
                    unsigned int* __restrict__ min1u,   // [B][NPTS] biased keys
                    unsigned int* __restrict__ min2u) { // [B][NPTS] biased keys
    const int lin = blockIdx.x;
    const int b   = lin & 7;          // XCD-aligned batch
    const int rest = lin >> 3;
    const int nt  = rest & 31;        // n-tile (128 rows)
    const int mh  = rest >> 5;        // m quarter (1024 cols)
    const int tid = threadIdx.x;
    const int wid = tid >> 6;
    const int l   = tid & 63;
    const int l15 = l & 15;
    const int lhi = l >> 4;

    __shared__ __align__(16) unsigned char btile[2][64 * 256]; // 2 x 16KB

    const __hip_bfloat16* bf1b = bf1 + (size_t)b * NPTS * DIM;
    const __hip_bfloat16* bf2b = bf2 + (size_t)b * NPTS * DIM;
    const float* sq2b = sq2 + b * NPTS;

    const int n0 = nt * 128 + wid * 32;  // wave's first row

    // A fragments: rows n0 + rt*16 + l15, k = ks*32 + lhi*8
    bf16x8 afrag[2][4];
    #pragma unroll
    for (int rt = 0; rt < 2; ++rt)
        #pragma unroll
        for (int ks = 0; ks < 4; ++ks)
            afrag[rt][ks] = *reinterpret_cast<const bf16x8*>(
                bf1b + (n0 + rt * 16 + l15) * DIM + ks * 32 + lhi * 8);

    // sq1 for accumulator rows: n0 + rt*16 + lhi*4 + j
    float sq1v[2][4];
    #pragma unroll
    for (int rt = 0; rt < 2; ++rt)
        #pragma unroll
        for (int j = 0; j < 4; ++j)
            sq1v[rt][j] = sq1[b * NPTS + n0 + rt * 16 + lhi * 4 + j];

    float rmin[2][4];
    #pragma unroll
    for (int rt = 0; rt < 2; ++rt)
        #pragma unroll
        for (int j = 0; j < 4; ++j) rmin[rt][j] = 3.4e38f;

    // wave-level stage of 64-row B tile at column m0 into buffer `buf`.
    // linear LDS slot (row,q) <- global column-block (q ^ (row&7)), so the
    // swizzled read  btile[row*256 + (kbyte ^ ((row&7)<<4))]  sees k=kbyte/2.
    auto STAGE = [&](int buf, int m0) {
        #pragma unroll
        for (int j = 0; j < 4; ++j) {
            const int c   = j * 256 + wid * 64 + l;   // [0, 1024)
            const int row = c >> 4;
            const int q   = c & 15;
            const __hip_bfloat16* src =
                bf2b + (size_t)(m0 + row) * DIM + (q ^ (row & 7)) * 8;
            stage16(src, &btile[buf][(j * 256 + wid * 64) * 16]);
        }
    };

    int cur = 0;
    STAGE(0, mh * 1024);
    __syncthreads();   // compiler drains vmcnt before the barrier

    for (int mt = 0; mt < 16; ++mt) {
        const int m0 = mh * 1024 + mt * 64;
        if (mt < 15) STAGE(cur ^ 1, m0 + 64);  // prefetch next tile

        // MFMA: acc = (-2*P1rows) x P2rows^T, K=128, 64 cols
        f32x4 acc[2][4];
        #pragma unroll
        for (int rt = 0; rt < 2; ++rt)
            #pragma unroll
            for (int ct = 0; ct < 4; ++ct) acc[rt][ct] = f32x4{0.f, 0.f, 0.f, 0.f};

        #pragma unroll
        for (int ks = 0; ks < 4; ++ks) {
            #pragma unroll
            for (int ct = 0; ct < 4; ++ct) {
                const int brow = ct * 16 + l15;
                const int kbyte = ks * 64 + lhi * 16;
                bf16x8 bfrag = *reinterpret_cast<const bf16x8*>(
                    &btile[cur][brow * 256 + (kbyte ^ ((brow & 7) << 4))]);
                #pragma unroll
                for (int rt = 0; rt < 2; ++rt)
                    acc[rt][ct] = __builtin_amdgcn_mfma_f32_16x16x32_bf16(
                        afrag[rt][ks], bfrag, acc[rt][ct], 0, 0, 0);
            }
        }

        // per-lane sq2 values for each col group (L1-resident)
        float s2v[4];
        #pragma unroll
        for (int ct = 0; ct < 4; ++ct) s2v[ct] = sq2b[m0 + ct * 16 + l15];

        // dir1: row-mins (min over cols), min3-friendly pairs over ct
        #pragma unroll
        for (int rt = 0; rt < 2; ++rt)
            #pragma unroll
            for (int j = 0; j < 4; ++j) {
                float r = rmin[rt][j];
                #pragma unroll
                for (int cp = 0; cp < 2; ++cp) {
                    const float t0 = acc[rt][2 * cp][j]     + s2v[2 * cp];
                    const float t1 = acc[rt][2 * cp + 1][j] + s2v[2 * cp + 1];
                    r = fminf(r, fminf(t0, t1));   // v_min3
                }
                rmin[rt][j] = r;
            }

        // dir2: col-mins (min over this wave's 32 rows), pairs over j
        float cmin[4];
        #pragma unroll
        for (int ct = 0; ct < 4; ++ct) {
            float c = 3.4e38f;
            #pragma unroll
            for (int rt = 0; rt < 2; ++rt)
                #pragma unroll
                for (int jp = 0; jp < 2; ++jp) {
                    const float u0 = sq1v[rt][2 * jp]     + acc[rt][ct][2 * jp];
                    const float u1 = sq1v[rt][2 * jp + 1] + acc[rt][ct][2 * jp + 1];
                    c = fminf(c, fminf(u0, u1));   // v_min3
                }
            cmin[ct] = c;
        }

        // fold the 4 lhi row-groups; all lanes end with the full col-min
        #pragma unroll
        for (int ct = 0; ct < 4; ++ct) {
            cmin[ct] = fminf(cmin[ct], __shfl_xor(cmin[ct], 16));
            cmin[ct] = fminf(cmin[ct], __shfl_xor(cmin[ct], 32));
        }
        // lane l owns col l of this tile: select its ct via cndmask chain
        // (compile-time-indexed reads only; runtime cmin[lhi] would spill)
        {
            float v = cmin[0];
            v = (lhi == 1) ? cmin[1] : v;
            v = (lhi == 2) ? cmin[2] : v;
            v = (lhi == 3) ? cmin[3] : v;
            atomicMin(&min2u[(size_t)b * NPTS + m0 + l],
                      __float_as_uint(v + FBIAS));
        }

        __syncthreads();   // next-tile loads landed AND everyone done reading cur
        cur ^= 1;
    }

    // dir1 finalize: reduce across lane bits 0..3 (cols), one atomic per row
    #pragma unroll
    for (int rt = 0; rt < 2; ++rt)
        #pragma unroll
        for (int j = 0; j < 4; ++j) {
            float v = rmin[rt][j];
            v = fminf(v, __shfl_xor(v, 1));
            v = fminf(v, __shfl_xor(v, 2));
            v = fminf(v, __shfl_xor(v, 4));
            v = fminf(v, __shfl_xor(v, 8));
            rmin[rt][j] = v;
        }
    if (l15 == 0) {
        #pragma unroll
        for (int rt = 0; rt < 2; ++rt)
            #pragma unroll
            for (int j = 0; j < 4; ++j)
                atomicMin(&min1u[(size_t)b * NPTS + n0 + rt * 16 + lhi * 4 + j],
                          __float_as_uint(rmin[rt][j] + FBIAS));
    }
}

// ------------- K3: combine, means, scalar out -------------------------------
// 256 blocks x 256 threads = 65536 = 2 * B * NPTS (exact, no guards)
__global__ void finalize_kernel(const unsigned int* __restrict__ min1u,
                                const unsigned int* __restrict__ min2u,
                                const float* __restrict__ sq1,
                                const float* __restrict__ sq2,
                                float* __restrict__ out) {
    const int tid = threadIdx.x;
    const int gid = blockIdx.x * 256 + tid;
    float sum;

    if (gid < BATCH * NPTS) {
        sum = (__uint_as_float(min1u[gid]) - FBIAS + sq1[gid])
              * (1.0f / (BATCH * NPTS));
    } else {
        const int idx = gid - BATCH * NPTS;
        sum = (__uint_as_float(min2u[idx]) - FBIAS + sq2[idx])
              * (1.0f / (BATCH * NPTS));
    }

    #pragma unroll
    for (int off = 1; off < 64; off <<= 1) sum += __shfl_xor(sum, off);
    __shared__ float wsum[4];
    if ((tid & 63) == 0) wsum[tid >> 6] = sum;
    __syncthreads();
    if (tid == 0) atomicAdd(out, wsum[0] + wsum[1] + wsum[2] + wsum[3]);
}

extern "C" void kernel_launch(void* const* d_in, const int* in_sizes, int n_in,
                              void* d_out, int out_size, void* d_ws, size_t ws_size,
                              hipStream_t stream) {
    const float* p1 = (const float*)d_in[0];
    const float* p2 = (const float*)d_in[1];
    float* out = (float*)d_out;

    const size_t npts_tot = (size_t)BATCH * NPTS;
    __hip_bfloat16* bf1 = (__hip_bfloat16*)d_ws;
    __hip_bfloat16* bf2 = bf1 + npts_tot * DIM;
    float* sq1 = (float*)(bf2 + npts_tot * DIM);
    float* sq2 = sq1 + npts_tot;
    unsigned int* min1u = (unsigned int*)(sq2 + npts_tot);  // [B][NPTS]
    unsigned int* min2u = min1u + npts_tot;                 // [B][NPTS]

    hipMemsetAsync(d_out, 0, sizeof(float), stream);
    hipMemsetAsync(min1u, 0xFF, npts_tot * 2 * sizeof(unsigned int), stream);

    prep_kernel<<<dim3(npts_tot / 4, 2), 256, 0, stream>>>(p1, p2, bf1, bf2, sq1, sq2);

    chamfer_tile_kernel<<<1024, 256, 0, stream>>>(bf1, bf2, sq1, sq2, min1u, min2u);

    finalize_kernel<<<256, 256, 0, stream>>>(min1u, min2u, sq1, sq2, out);
}

// Round 8
// 131.570 us; speedup vs baseline: 1.2390x; 1.0620x over previous
//
#include <hip/hip_runtime.h>
#include <hip/hip_bf16.h>

// Chamfer distance: B=8, N=M=4096, D=128, fp32 inputs, scalar fp32 out.
// dist[b,n,m] = ||p1||^2 + ||p2||^2 - 2*p1.p2
// bf1 holds (-2*p1) in bf16, so MFMA acc = -2*cross directly.
// Mins via biased-float-as-uint atomicMin (bias 16384 -> all keys positive;
// uint order == float order for positive floats).

#define BATCH 8
#define NPTS 4096
#define DIM 128
#define FBIAS 16384.0f

using bf16x8 = __attribute__((ext_vector_type(8))) short;
using f32x4  = __attribute__((ext_vector_type(4))) float;

// ------------- K1: fp32 -> bf16 (p1 scaled by -2) + exact fp32 norms --------
__global__ void prep_kernel(const float* __restrict__ p1,
                            const float* __restrict__ p2,
                            __hip_bfloat16* __restrict__ b1,
                            __hip_bfloat16* __restrict__ b2,
                            float* __restrict__ s1,
                            float* __restrict__ s2) {
    const int arr = blockIdx.y;
    const float* src = arr ? p2 : p1;
    __hip_bfloat16* dst = arr ? b2 : b1;
    float* sq = arr ? s2 : s1;
    const float scale = arr ? 1.0f : -2.0f;

    const int wid = threadIdx.x >> 6;
    const int l   = threadIdx.x & 63;
    const int p   = blockIdx.x * 4 + wid;   // one wave per point
    const float2 v = *reinterpret_cast<const float2*>(src + (size_t)p * DIM + l * 2);
    float s = v.x * v.x + v.y * v.y;        // norm from ORIGINAL values
    __hip_bfloat162 h = __float22bfloat162_rn(make_float2(v.x * scale, v.y * scale));
    *reinterpret_cast<__hip_bfloat162*>(dst + (size_t)p * DIM + l * 2) = h;
    #pragma unroll
    for (int off = 1; off < 64; off <<= 1) s += __shfl_xor(s, off);
    if (l == 0) sq[p] = s;
}

// async global->LDS, 16B per lane; lds base must be wave-uniform.
__device__ __forceinline__ void stage16(const __hip_bfloat16* g, void* lds) {
    __builtin_amdgcn_global_load_lds(
        (const __attribute__((address_space(1))) void*)g,
        (__attribute__((address_space(3))) void*)lds, 16, 0, 0);
}

// ------------- K2: tiled GEMM + fused directional mins ----------------------
// 1-D grid of 1024 blocks; b = id&7 so XCD k (round-robin dispatch) only
// touches batch k -> per-XCD L2 working set = 2MB bf16 data (R6: FETCH 8.4MB).
// Block: 128 rows x 1024 cols as 16 m-tiles of 64 cols. Wave: 32 rows.
// B-tile (64 rows x 256B = 16KB) double-buffered, staged via global_load_lds
// with the XOR swizzle applied on the SOURCE address (gload_lds writes
// linearly); next tile prefetched before computing the current one.
//
// R7 LESSON: K2 was 60us at occupancy 19% AND 31% -> not occupancy-bound.
// The invariant cost was the per-tile __syncthreads draining vmcnt(0) over
// the per-tile min2 global store/atomic = forced L2 round-trip every tile.
// THIS round: NO global writes inside the tile loop. Col-mins accumulate in
// a 4KB LDS array via shared-memory atomicMin (lgkmcnt, ~tens of cycles);
// one global atomicMin pass per block at the end. The per-tile barrier now
// only waits the 4 prefetch loads (issued ~700cy earlier, 97% L2-hit).
//
// OCCUPANCY: 2nd __launch_bounds__ arg pins waves/EU ((256,2) rounds all
// ~19-21%, (256,4) rounds 31-43%). (256,4) fits this body (VGPR=64, FETCH
// shows no spill blowup). FETCH_SIZE is the spill canary.
__global__ void __launch_bounds__(256, 4)
chamfer_tile_kernel(const __hip_bfloat16* __restrict__ bf1,
                    const __hip_bfloat16* __restrict__ bf2,
                    const float* __restrict__ sq1,
                    const float* __restrict__ sq2,
                    unsigned int* __restrict__ min1u,   // [B][NPTS] biased keys
                    unsigned int* __restrict__ min2u) { // [B][NPTS] biased keys
    const int lin = blockIdx.x;
    const int b   = lin & 7;          // XCD-aligned batch
    const int rest = lin >> 3;
    const int nt  = rest & 31;        // n-tile (128 rows)
    const int mh  = rest >> 5;        // m quarter (1024 cols)
    const int tid = threadIdx.x;
    const int wid = tid >> 6;
    const int l   = tid & 63;
    const int l15 = l & 15;
    const int lhi = l >> 4;

    __shared__ __align__(16) unsigned char btile[2][64 * 256]; // 2 x 16KB
    __shared__ unsigned int colminu[1024];                     // 4KB col-min acc

    const __hip_bfloat16* bf1b = bf1 + (size_t)b * NPTS * DIM;
    const __hip_bfloat16* bf2b = bf2 + (size_t)b * NPTS * DIM;
    const float* sq2b = sq2 + b * NPTS;

    const int n0 = nt * 128 + wid * 32;  // wave's first row

    // A fragments: rows n0 + rt*16 + l15, k = ks*32 + lhi*8
    bf16x8 afrag[2][4];
    #pragma unroll
    for (int rt = 0; rt < 2; ++rt)
        #pragma unroll
        for (int ks = 0; ks < 4; ++ks)
            afrag[rt][ks] = *reinterpret_cast<const bf16x8*>(
                bf1b + (n0 + rt * 16 + l15) * DIM + ks * 32 + lhi * 8);

    // sq1 for accumulator rows: n0 + rt*16 + lhi*4 + j
    float sq1v[2][4];
    #pragma unroll
    for (int rt = 0; rt < 2; ++rt)
        #pragma unroll
        for (int j = 0; j < 4; ++j)
            sq1v[rt][j] = sq1[b * NPTS + n0 + rt * 16 + lhi * 4 + j];

    float rmin[2][4];
    #pragma unroll
    for (int rt = 0; rt < 2; ++rt)
        #pragma unroll
        for (int j = 0; j < 4; ++j) rmin[rt][j] = 3.4e38f;

    // wave-level stage of 64-row B tile at column m0 into buffer `buf`.
    // linear LDS slot (row,q) <- global column-block (q ^ (row&7)), so the
    // swizzled read  btile[row*256 + (kbyte ^ ((row&7)<<4))]  sees k=kbyte/2.
    auto STAGE = [&](int buf, int m0) {
        #pragma unroll
        for (int j = 0; j < 4; ++j) {
            const int c   = j * 256 + wid * 64 + l;   // [0, 1024)
            const int row = c >> 4;
            const int q   = c & 15;
            const __hip_bfloat16* src =
                bf2b + (size_t)(m0 + row) * DIM + (q ^ (row & 7)) * 8;
            stage16(src, &btile[buf][(j * 256 + wid * 64) * 16]);
        }
    };

    int cur = 0;
    STAGE(0, mh * 1024);
    // init LDS col-min accumulator while the first tile's loads fly
    #pragma unroll
    for (int i = 0; i < 4; ++i) colminu[i * 256 + tid] = 0xFFFFFFFFu;
    __syncthreads();   // drains the first STAGE + covers colminu init

    for (int mt = 0; mt < 16; ++mt) {
        const int m0 = mh * 1024 + mt * 64;
        if (mt < 15) STAGE(cur ^ 1, m0 + 64);  // prefetch next tile

        // MFMA: acc = (-2*P1rows) x P2rows^T, K=128, 64 cols
        f32x4 acc[2][4];
        #pragma unroll
        for (int rt = 0; rt < 2; ++rt)
            #pragma unroll
            for (int ct = 0; ct < 4; ++ct) acc[rt][ct] = f32x4{0.f, 0.f, 0.f, 0.f};

        #pragma unroll
        for (int ks = 0; ks < 4; ++ks) {
            #pragma unroll
            for (int ct = 0; ct < 4; ++ct) {
                const int brow = ct * 16 + l15;
                const int kbyte = ks * 64 + lhi * 16;
                bf16x8 bfrag = *reinterpret_cast<const bf16x8*>(
                    &btile[cur][brow * 256 + (kbyte ^ ((brow & 7) << 4))]);
                #pragma unroll
                for (int rt = 0; rt < 2; ++rt)
                    acc[rt][ct] = __builtin_amdgcn_mfma_f32_16x16x32_bf16(
                        afrag[rt][ks], bfrag, acc[rt][ct], 0, 0, 0);
            }
        }

        // per-lane sq2 values for each col group (L1-resident)
        float s2v[4];
        #pragma unroll
        for (int ct = 0; ct < 4; ++ct) s2v[ct] = sq2b[m0 + ct * 16 + l15];

        // dir1: row-mins (min over cols), min3-friendly pairs over ct
        #pragma unroll
        for (int rt = 0; rt < 2; ++rt)
            #pragma unroll
            for (int j = 0; j < 4; ++j) {
                float r = rmin[rt][j];
                #pragma unroll
                for (int cp = 0; cp < 2; ++cp) {
                    const float t0 = acc[rt][2 * cp][j]     + s2v[2 * cp];
                    const float t1 = acc[rt][2 * cp + 1][j] + s2v[2 * cp + 1];
                    r = fminf(r, fminf(t0, t1));   // v_min3
                }
                rmin[rt][j] = r;
            }

        // dir2: col-mins (min over this wave's 32 rows), pairs over j
        float cmin[4];
        #pragma unroll
        for (int ct = 0; ct < 4; ++ct) {
            float c = 3.4e38f;
            #pragma unroll
            for (int rt = 0; rt < 2; ++rt)
                #pragma unroll
                for (int jp = 0; jp < 2; ++jp) {
                    const float u0 = sq1v[rt][2 * jp]     + acc[rt][ct][2 * jp];
                    const float u1 = sq1v[rt][2 * jp + 1] + acc[rt][ct][2 * jp + 1];
                    c = fminf(c, fminf(u0, u1));   // v_min3
                }
            cmin[ct] = c;
        }

        // fold the 4 lhi row-groups; all lanes end with the full col-min
        #pragma unroll
        for (int ct = 0; ct < 4; ++ct) {
            cmin[ct] = fminf(cmin[ct], __shfl_xor(cmin[ct], 16));
            cmin[ct] = fminf(cmin[ct], __shfl_xor(cmin[ct], 32));
        }
        // lane l owns col l of this tile: select its ct via cndmask chain,
        // then fold into the LDS accumulator (ds_min, NOT a global atomic --
        // keeps the tile loop free of vmem writes so the barrier drain only
        // covers the prefetch loads).
        {
            float v = cmin[0];
            v = (lhi == 1) ? cmin[1] : v;
            v = (lhi == 2) ? cmin[2] : v;
            v = (lhi == 3) ? cmin[3] : v;
            atomicMin(&colminu[mt * 64 + l], __float_as_uint(v + FBIAS));
        }

        __syncthreads();   // next-tile loads landed AND everyone done reading cur
        cur ^= 1;
    }

    // dir2 finalize: one global atomicMin per column, once per block
    #pragma unroll
    for (int i = 0; i < 4; ++i) {
        const int c = i * 256 + tid;
        atomicMin(&min2u[(size_t)b * NPTS + mh * 1024 + c], colminu[c]);
    }

    // dir1 finalize: reduce across lane bits 0..3 (cols), one atomic per row
    #pragma unroll
    for (int rt = 0; rt < 2; ++rt)
        #pragma unroll
        for (int j = 0; j < 4; ++j) {
            float v = rmin[rt][j];
            v = fminf(v, __shfl_xor(v, 1));
            v = fminf(v, __shfl_xor(v, 2));
            v = fminf(v, __shfl_xor(v, 4));
            v = fminf(v, __shfl_xor(v, 8));
            rmin[rt][j] = v;
        }
    if (l15 == 0) {
        #pragma unroll
        for (int rt = 0; rt < 2; ++rt)
            #pragma unroll
            for (int j = 0; j < 4; ++j)
                atomicMin(&min1u[(size_t)b * NPTS + n0 + rt * 16 + lhi * 4 + j],
                          __float_as_uint(rmin[rt][j] + FBIAS));
    }
}

// ------------- K3: combine, means, scalar out -------------------------------
// 256 blocks x 256 threads = 65536 = 2 * B * NPTS (exact, no guards)
__global__ void finalize_kernel(const unsigned int* __restrict__ min1u,
                                const unsigned int* __restrict__ min2u,
                                const float* __restrict__ sq1,
                                const float* __restrict__ sq2,
                                float* __restrict__ out) {
    const int tid = threadIdx.x;
    const int gid = blockIdx.x * 256 + tid;
    float sum;

    if (gid < BATCH * NPTS) {
        sum = (__uint_as_float(min1u[gid]) - FBIAS + sq1[gid])
              * (1.0f / (BATCH * NPTS));
    } else {
        const int idx = gid - BATCH * NPTS;
        sum = (__uint_as_float(min2u[idx]) - FBIAS + sq2[idx])
              * (1.0f / (BATCH * NPTS));
    }

    #pragma unroll
    for (int off = 1; off < 64; off <<= 1) sum += __shfl_xor(sum, off);
    __shared__ float wsum[4];
    if ((tid & 63) == 0) wsum[tid >> 6] = sum;
    __syncthreads();
    if (tid == 0) atomicAdd(out, wsum[0] + wsum[1] + wsum[2] + wsum[3]);
}

extern "C" void kernel_launch(void* const* d_in, const int* in_sizes, int n_in,
                              void* d_out, int out_size, void* d_ws, size_t ws_size,
                              hipStream_t stream) {
    const float* p1 = (const float*)d_in[0];
    const float* p2 = (const float*)d_in[1];
    float* out = (float*)d_out;

    const size_t npts_tot = (size_t)BATCH * NPTS;
    __hip_bfloat16* bf1 = (__hip_bfloat16*)d_ws;
    __hip_bfloat16* bf2 = bf1 + npts_tot * DIM;
    float* sq1 = (float*)(bf2 + npts_tot * DIM);
    float* sq2 = sq1 + npts_tot;
    unsigned int* min1u = (unsigned int*)(sq2 + npts_tot);  // [B][NPTS]
    unsigned int* min2u = min1u + npts_tot;                 // [B][NPTS]

    hipMemsetAsync(d_out, 0, sizeof(float), stream);
    hipMemsetAsync(min1u, 0xFF, npts_tot * 2 * sizeof(unsigned int), stream);

    prep_kernel<<<dim3(npts_tot / 4, 2), 256, 0, stream>>>(p1, p2, bf1, bf2, sq1, sq2);

    chamfer_tile_kernel<<<1024, 256, 0, stream>>>(bf1, bf2, sq1, sq2, min1u, min2u);

    finalize_kernel<<<256, 256, 0, stream>>>(min1u, min2u, sq1, sq2, out);
}

// Round 9
// 129.904 us; speedup vs baseline: 1.2549x; 1.0128x over previous
//
#include <hip/hip_runtime.h>
#include <hip/hip_bf16.h>

// Chamfer distance: B=8, N=M=4096, D=128, fp32 inputs, scalar fp32 out.
// dist[b,n,m] = ||p1||^2 + ||p2||^2 - 2*p1.p2
// bf1 holds (-2*p1) in bf16, so MFMA acc = -2*cross directly.
// Mins via biased-float-as-uint atomicMin (bias 16384 -> all keys positive;
// uint order == float order for positive floats).

#define BATCH 8
#define NPTS 4096
#define DIM 128
#define FBIAS 16384.0f

using bf16x8 = __attribute__((ext_vector_type(8))) short;
using f32x4  = __attribute__((ext_vector_type(4))) float;

// ------------- K1: fp32 -> bf16 (p1 scaled by -2) + exact fp32 norms --------
__global__ void prep_kernel(const float* __restrict__ p1,
                            const float* __restrict__ p2,
                            __hip_bfloat16* __restrict__ b1,
                            __hip_bfloat16* __restrict__ b2,
                            float* __restrict__ s1,
                            float* __restrict__ s2) {
    const int arr = blockIdx.y;
    const float* src = arr ? p2 : p1;
    __hip_bfloat16* dst = arr ? b2 : b1;
    float* sq = arr ? s2 : s1;
    const float scale = arr ? 1.0f : -2.0f;

    const int wid = threadIdx.x >> 6;
    const int l   = threadIdx.x & 63;
    const int p   = blockIdx.x * 4 + wid;   // one wave per point
    const float2 v = *reinterpret_cast<const float2*>(src + (size_t)p * DIM + l * 2);
    float s = v.x * v.x + v.y * v.y;        // norm from ORIGINAL values
    __hip_bfloat162 h = __float22bfloat162_rn(make_float2(v.x * scale, v.y * scale));
    *reinterpret_cast<__hip_bfloat162*>(dst + (size_t)p * DIM + l * 2) = h;
    #pragma unroll
    for (int off = 1; off < 64; off <<= 1) s += __shfl_xor(s, off);
    if (l == 0) sq[p] = s;
}

// async global->LDS, 16B per lane; lds base must be wave-uniform.
__device__ __forceinline__ void stage16(const __hip_bfloat16* g, void* lds) {
    __builtin_amdgcn_global_load_lds(
        (const __attribute__((address_space(1))) void*)g,
        (__attribute__((address_space(3))) void*)lds, 16, 0, 0);
}

// ------------- K2: tiled GEMM + fused directional mins ----------------------
// 1-D grid of 1024 blocks; b = id&7 (XCD-aligned batch; FETCH 8.4MB in R6).
// Block: 128 rows x 1024 cols as 16 m-tiles of 64 cols. Wave: 32 rows.
// B-tile double-buffered via global_load_lds (swizzle on SOURCE address).
//
// R8 -> R9: per-tile serial chain (dsread -> 4-deep MFMA -> full fold ->
// shfl -> ds_atomic -> barrier) was the stall (issue work 16us, wall 51us).
// Pipeline it: (a) dir2 shfl+select+ds_atomic tail DEFERRED one tile,
// executed right after next tile's STAGE issue (fills load window);
// (b) s2v prefetched one tile ahead; (c) MFMAs grouped per ct-PAIR with the
// fold immediately after each pair, so VALU of pair 0 overlaps MFMA of
// pair 1. Extra state: cminP[4] + s2v double = 8 regs.
//
// OCCUPANCY: 2nd __launch_bounds__ arg pins waves/EU ((256,2) ~19-21%,
// (256,4) 31-43%). 8 waves/EU impossible (needs <=64 regs; body ~110).
// FETCH_SIZE is the spill canary (R3: spill -> 239MB).
__global__ void __launch_bounds__(256, 4)
chamfer_tile_kernel(const __hip_bfloat16* __restrict__ bf1,
                    const __hip_bfloat16* __restrict__ bf2,
                    const float* __restrict__ sq1,
                    const float* __restrict__ sq2,
                    unsigned int* __restrict__ min1u,   // [B][NPTS] biased keys
                    unsigned int* __restrict__ min2u) { // [B][NPTS] biased keys
    const int lin = blockIdx.x;
    const int b   = lin & 7;          // XCD-aligned batch
    const int rest = lin >> 3;
    const int nt  = rest & 31;        // n-tile (128 rows)
    const int mh  = rest >> 5;        // m quarter (1024 cols)
    const int tid = threadIdx.x;
    const int wid = tid >> 6;
    const int l   = tid & 63;
    const int l15 = l & 15;
    const int lhi = l >> 4;
    const int base = mh * 1024;

    __shared__ __align__(16) unsigned char btile[2][64 * 256]; // 2 x 16KB
    __shared__ unsigned int colminu[1024];                     // 4KB col-min acc

    const __hip_bfloat16* bf1b = bf1 + (size_t)b * NPTS * DIM;
    const __hip_bfloat16* bf2b = bf2 + (size_t)b * NPTS * DIM;
    const float* sq2b = sq2 + b * NPTS;

    const int n0 = nt * 128 + wid * 32;  // wave's first row

    // A fragments: rows n0 + rt*16 + l15, k = ks*32 + lhi*8
    bf16x8 afrag[2][4];
    #pragma unroll
    for (int rt = 0; rt < 2; ++rt)
        #pragma unroll
        for (int ks = 0; ks < 4; ++ks)
            afrag[rt][ks] = *reinterpret_cast<const bf16x8*>(
                bf1b + (n0 + rt * 16 + l15) * DIM + ks * 32 + lhi * 8);

    // sq1 for accumulator rows: n0 + rt*16 + lhi*4 + j
    float sq1v[2][4];
    #pragma unroll
    for (int rt = 0; rt < 2; ++rt)
        #pragma unroll
        for (int j = 0; j < 4; ++j)
            sq1v[rt][j] = sq1[b * NPTS + n0 + rt * 16 + lhi * 4 + j];

    float rmin[2][4];
    #pragma unroll
    for (int rt = 0; rt < 2; ++rt)
        #pragma unroll
        for (int j = 0; j < 4; ++j) rmin[rt][j] = 3.4e38f;

    // wave-level stage of 64-row B tile at column m0 into buffer `buf`.
    // linear LDS slot (row,q) <- global column-block (q ^ (row&7)), so the
    // swizzled read  btile[row*256 + (kbyte ^ ((row&7)<<4))]  sees k=kbyte/2.
    auto STAGE = [&](int buf, int m0) {
        #pragma unroll
        for (int j = 0; j < 4; ++j) {
            const int c   = j * 256 + wid * 64 + l;   // [0, 1024)
            const int row = c >> 4;
            const int q   = c & 15;
            const __hip_bfloat16* src =
                bf2b + (size_t)(m0 + row) * DIM + (q ^ (row & 7)) * 8;
            stage16(src, &btile[buf][(j * 256 + wid * 64) * 16]);
        }
    };

    // deferred dir2 tail: fold lhi groups, pick this lane's column, ds-min.
    auto TAIL = [&](const float* cp, int mtIdx) {
        float c0 = fminf(cp[0], __shfl_xor(cp[0], 16));
        float c1 = fminf(cp[1], __shfl_xor(cp[1], 16));
        float c2 = fminf(cp[2], __shfl_xor(cp[2], 16));
        float c3 = fminf(cp[3], __shfl_xor(cp[3], 16));
        c0 = fminf(c0, __shfl_xor(c0, 32));
        c1 = fminf(c1, __shfl_xor(c1, 32));
        c2 = fminf(c2, __shfl_xor(c2, 32));
        c3 = fminf(c3, __shfl_xor(c3, 32));
        float v = c0;
        v = (lhi == 1) ? c1 : v;
        v = (lhi == 2) ? c2 : v;
        v = (lhi == 3) ? c3 : v;
        atomicMin(&colminu[mtIdx * 64 + l], __float_as_uint(v + FBIAS));
    };

    int cur = 0;
    STAGE(0, base);
    // init LDS col-min accumulator + preload tile0's sq2 while loads fly
    #pragma unroll
    for (int i = 0; i < 4; ++i) colminu[i * 256 + tid] = 0xFFFFFFFFu;
    float s2vN[4], s2vC[4];
    #pragma unroll
    for (int ct = 0; ct < 4; ++ct) s2vN[ct] = sq2b[base + ct * 16 + l15];
    __syncthreads();   // drains the first STAGE + covers colminu init

    float cminP[4];

    for (int mt = 0; mt < 16; ++mt) {
        const int m0 = base + mt * 64;
        if (mt < 15) STAGE(cur ^ 1, m0 + 64);  // prefetch next tile

        // deferred dir2 tail from previous tile (independent of this tile's
        // MFMAs; runs while the prefetch loads are in flight)
        if (mt > 0) TAIL(cminP, mt - 1);

        // rotate prefetched sq2 values; prefetch next tile's
        #pragma unroll
        for (int ct = 0; ct < 4; ++ct) s2vC[ct] = s2vN[ct];
        if (mt < 15) {
            #pragma unroll
            for (int ct = 0; ct < 4; ++ct)
                s2vN[ct] = sq2b[m0 + 64 + ct * 16 + l15];
        }

        // MFMA per ct-PAIR with immediate fold (VALU of pair 0 overlaps
        // MFMA of pair 1)
        f32x4 acc[2][4];
        float cmin[4];
        #pragma unroll
        for (int cp = 0; cp < 2; ++cp) {
            #pragma unroll
            for (int cc = 0; cc < 2; ++cc) {
                const int ct = 2 * cp + cc;
                acc[0][ct] = f32x4{0.f, 0.f, 0.f, 0.f};
                acc[1][ct] = f32x4{0.f, 0.f, 0.f, 0.f};
                const int brow = ct * 16 + l15;
                #pragma unroll
                for (int ks = 0; ks < 4; ++ks) {
                    const int kbyte = ks * 64 + lhi * 16;
                    bf16x8 bfrag = *reinterpret_cast<const bf16x8*>(
                        &btile[cur][brow * 256 + (kbyte ^ ((brow & 7) << 4))]);
                    #pragma unroll
                    for (int rt = 0; rt < 2; ++rt)
                        acc[rt][ct] = __builtin_amdgcn_mfma_f32_16x16x32_bf16(
                            afrag[rt][ks], bfrag, acc[rt][ct], 0, 0, 0);
                }
            }
            // dir1: row-mins for this ct pair (min3 pairs)
            #pragma unroll
            for (int rt = 0; rt < 2; ++rt)
                #pragma unroll
                for (int j = 0; j < 4; ++j) {
                    const float t0 = acc[rt][2 * cp][j]     + s2vC[2 * cp];
                    const float t1 = acc[rt][2 * cp + 1][j] + s2vC[2 * cp + 1];
                    rmin[rt][j] = fminf(rmin[rt][j], fminf(t0, t1)); // v_min3
                }
            // dir2: col-mins for the two cts of this pair
            #pragma unroll
            for (int cc = 0; cc < 2; ++cc) {
                const int ct = 2 * cp + cc;
                float c = 3.4e38f;
                #pragma unroll
                for (int rt = 0; rt < 2; ++rt)
                    #pragma unroll
                    for (int jp = 0; jp < 2; ++jp) {
                        const float u0 = sq1v[rt][2 * jp]     + acc[rt][ct][2 * jp];
                        const float u1 = sq1v[rt][2 * jp + 1] + acc[rt][ct][2 * jp + 1];
                        c = fminf(c, fminf(u0, u1));   // v_min3
                    }
                cmin[ct] = c;
            }
        }
        #pragma unroll
        for (int ct = 0; ct < 4; ++ct) cminP[ct] = cmin[ct];

        __syncthreads();   // next-tile loads landed AND everyone done reading cur
        cur ^= 1;
    }

    // flush the last tile's deferred tail
    TAIL(cminP, 15);
    __syncthreads();

    // dir2 finalize: one global atomicMin per column, once per block
    #pragma unroll
    for (int i = 0; i < 4; ++i) {
        const int c = i * 256 + tid;
        atomicMin(&min2u[(size_t)b * NPTS + base + c], colminu[c]);
    }

    // dir1 finalize: reduce across lane bits 0..3 (cols), one atomic per row
    #pragma unroll
    for (int rt = 0; rt < 2; ++rt)
        #pragma unroll
        for (int j = 0; j < 4; ++j) {
            float v = rmin[rt][j];
            v = fminf(v, __shfl_xor(v, 1));
            v = fminf(v, __shfl_xor(v, 2));
            v = fminf(v, __shfl_xor(v, 4));
            v = fminf(v, __shfl_xor(v, 8));
            rmin[rt][j] = v;
        }
    if (l15 == 0) {
        #pragma unroll
        for (int rt = 0; rt < 2; ++rt)
            #pragma unroll
            for (int j = 0; j < 4; ++j)
                atomicMin(&min1u[(size_t)b * NPTS + n0 + rt * 16 + lhi * 4 + j],
                          __float_as_uint(rmin[rt][j] + FBIAS));
    }
}

// ------------- K3: combine, means, scalar out -------------------------------
// 256 blocks x 256 threads = 65536 = 2 * B * NPTS (exact, no guards)
__global__ void finalize_kernel(const unsigned int* __restrict__ min1u,
                                const unsigned int* __restrict__ min2u,
                                const float* __restrict__ sq1,
                                const float* __restrict__ sq2,
                                float* __restrict__ out) {
    const int tid = threadIdx.x;
    const int gid = blockIdx.x * 256 + tid;
    float sum;

    if (gid < BATCH * NPTS) {
        sum = (__uint_as_float(min1u[gid]) - FBIAS + sq1[gid])
              * (1.0f / (BATCH * NPTS));
    } else {
        const int idx = gid - BATCH * NPTS;
        sum = (__uint_as_float(min2u[idx]) - FBIAS + sq2[idx])
              * (1.0f / (BATCH * NPTS));
    }

    #pragma unroll
    for (int off = 1; off < 64; off <<= 1) sum += __shfl_xor(sum, off);
    __shared__ float wsum[4];
    if ((tid & 63) == 0) wsum[tid >> 6] = sum;
    __syncthreads();
    if (tid == 0) atomicAdd(out, wsum[0] + wsum[1] + wsum[2] + wsum[3]);
}

extern "C" void kernel_launch(void* const* d_in, const int* in_sizes, int n_in,
                              void* d_out, int out_size, void* d_ws, size_t ws_size,
                              hipStream_t stream) {
    const float* p1 = (const float*)d_in[0];
    const float* p2 = (const float*)d_in[1];
    float* out = (float*)d_out;

    const size_t npts_tot = (size_t)BATCH * NPTS;
    __hip_bfloat16* bf1 = (__hip_bfloat16*)d_ws;
    __hip_bfloat16* bf2 = bf1 + npts_tot * DIM;
    float* sq1 = (float*)(bf2 + npts_tot * DIM);
    float* sq2 = sq1 + npts_tot;
    unsigned int* min1u = (unsigned int*)(sq2 + npts_tot);  // [B][NPTS]
    unsigned int* min2u = min1u + npts_tot;                 // [B][NPTS]

    hipMemsetAsync(d_out, 0, sizeof(float), stream);
    hipMemsetAsync(min1u, 0xFF, npts_tot * 2 * sizeof(unsigned int), stream);

    prep_kernel<<<dim3(npts_tot / 4, 2), 256, 0, stream>>>(p1, p2, bf1, bf2, sq1, sq2);

    chamfer_tile_kernel<<<1024, 256, 0, stream>>>(bf1, bf2, sq1, sq2, min1u, min2u);

    finalize_kernel<<<256, 256, 0, stream>>>(min1u, min2u, sq1, sq2, out);
}